// Round 1
// baseline (327.322 us; speedup 1.0000x reference)
//
#include <hip/hip_runtime.h>

typedef unsigned short u16;
typedef unsigned int u32;
typedef u16 u16x4 __attribute__((ext_vector_type(4)));
typedef u16 u16x8 __attribute__((ext_vector_type(8)));
typedef u32 u32x4 __attribute__((ext_vector_type(4)));
typedef float f32x4 __attribute__((ext_vector_type(4)));
typedef __bf16 bf16x8 __attribute__((ext_vector_type(8)));

#define B_N 4
#define S_N 1024
#define E_N 1024
#define H_N 16
#define D_N 64
#define F_N 4096
#define NTOK 4096

static __device__ __forceinline__ u16 f2bf(float f) {
  u32 u = __builtin_bit_cast(u32, f);
  return (u16)((u + 0x7fffu + ((u >> 16) & 1u)) >> 16);
}
static __device__ __forceinline__ float bf2f(u16 v) {
  return __builtin_bit_cast(float, ((u32)v) << 16);
}
static __device__ __forceinline__ f32x4 mfma16(u16x8 a, u16x8 b, f32x4 c) {
  return __builtin_amdgcn_mfma_f32_16x16x32_bf16(
      __builtin_bit_cast(bf16x8, a), __builtin_bit_cast(bf16x8, b), c, 0, 0, 0);
}

// ---------------- f32 -> bf16 conversion ----------------
__global__ __launch_bounds__(256) void cvt_kernel(const float* __restrict__ in,
                                                  u16* __restrict__ out, int n4) {
  int i = blockIdx.x * 256 + threadIdx.x;
  if (i < n4) {
    float4 v = ((const float4*)in)[i];
    u16x4 o;
    o[0] = f2bf(v.x); o[1] = f2bf(v.y); o[2] = f2bf(v.z); o[3] = f2bf(v.w);
    ((u16x4*)out)[i] = o;
  }
}

// ---------------- GEMM: C[M,N] = A[M,K] @ B[N,K]^T (bf16 in, f32 acc) ----------------
// MODE 0: Q proj  -> out0[b,h,s,d] bf16
// MODE 1: K proj  -> out0 = Kc = v*cos(2p)/8, out1 = Ks = v*sin(2p)/8  [b,h,s,d]
// MODE 2: V proj  -> out0 = VcT = v*cos(p), out1 = VsT = v*sin(p)      [b,h,d,s]
// MODE 3: FFN1    -> out0[r,n] = bf16(relu(v + b1[n]))
// MODE 4: FFN2    -> fout[r,n] = v + b2[n]
template <int MODE>
__global__ __launch_bounds__(256) void gemm_bt(
    const u16* __restrict__ A, const u16* __restrict__ Bm, int M, int N, int K,
    float* __restrict__ fout, u16* __restrict__ out0, u16* __restrict__ out1,
    const float* __restrict__ phase, const float* __restrict__ biasp) {
  __shared__ u16 As[2][128 * 32];
  __shared__ u16 Bs[2][128 * 32];
  const int tid = threadIdx.x;
  const int lane = tid & 63;
  const int wv = tid >> 6;
  const int wr = wv >> 1, wc = wv & 1;
  const int bx = blockIdx.x, by = blockIdx.y;
  const int l15 = lane & 15, l4 = lane >> 4;

  f32x4 z4 = {0.f, 0.f, 0.f, 0.f};
  f32x4 acc[4][4];
#pragma unroll
  for (int m = 0; m < 4; ++m)
#pragma unroll
    for (int n = 0; n < 4; ++n) acc[m][n] = z4;

  int rr[2], cc4[2];
#pragma unroll
  for (int i = 0; i < 2; ++i) {
    int lin = i * 256 + tid;
    rr[i] = lin >> 2;
    cc4[i] = lin & 3;
  }
  const u16* Ab = A + (size_t)(by * 128) * K;
  const u16* Bb = Bm + (size_t)(bx * 128) * K;
  u32x4 ra[2], rb[2];

#pragma unroll
  for (int i = 0; i < 2; ++i) {
    ra[i] = *(const u32x4*)(Ab + (size_t)rr[i] * K + cc4[i] * 8);
    rb[i] = *(const u32x4*)(Bb + (size_t)rr[i] * K + cc4[i] * 8);
  }
#pragma unroll
  for (int i = 0; i < 2; ++i) {
    int off = (rr[i] * 64 + cc4[i] * 16) ^ (((rr[i] >> 1) & 3) << 4);
    *(u32x4*)((char*)As[0] + off) = ra[i];
    *(u32x4*)((char*)Bs[0] + off) = rb[i];
  }
  __syncthreads();

  const int KT = K >> 5;
  int cur = 0;
  for (int kt = 0; kt < KT; ++kt) {
    if (kt + 1 < KT) {
#pragma unroll
      for (int i = 0; i < 2; ++i) {
        ra[i] = *(const u32x4*)(Ab + (size_t)rr[i] * K + (kt + 1) * 32 + cc4[i] * 8);
        rb[i] = *(const u32x4*)(Bb + (size_t)rr[i] * K + (kt + 1) * 32 + cc4[i] * 8);
      }
    }
    u16x8 af[4], bf4[4];
#pragma unroll
    for (int m = 0; m < 4; ++m) {
      int row = wr * 64 + m * 16 + l15;
      int off = (row * 64 + (l4 << 4)) ^ (((row >> 1) & 3) << 4);
      af[m] = *(const u16x8*)((const char*)As[cur] + off);
    }
#pragma unroll
    for (int n = 0; n < 4; ++n) {
      int row = wc * 64 + n * 16 + l15;
      int off = (row * 64 + (l4 << 4)) ^ (((row >> 1) & 3) << 4);
      bf4[n] = *(const u16x8*)((const char*)Bs[cur] + off);
    }
#pragma unroll
    for (int m = 0; m < 4; ++m)
#pragma unroll
      for (int n = 0; n < 4; ++n) acc[m][n] = mfma16(af[m], bf4[n], acc[m][n]);

    if (kt + 1 < KT) {
      int nxt = cur ^ 1;
#pragma unroll
      for (int i = 0; i < 2; ++i) {
        int off = (rr[i] * 64 + cc4[i] * 16) ^ (((rr[i] >> 1) & 3) << 4);
        *(u32x4*)((char*)As[nxt] + off) = ra[i];
        *(u32x4*)((char*)Bs[nxt] + off) = rb[i];
      }
      __syncthreads();
      cur = nxt;
    }
  }

  // epilogue
  const int row0 = by * 128 + wr * 64;
  const int col0 = bx * 128 + wc * 64;
#pragma unroll
  for (int n = 0; n < 4; ++n) {
    const int gc = col0 + n * 16 + l15;
    float c1 = 0.f, s1 = 0.f, bv = 0.f;
    if (MODE == 1) { __sincosf(2.f * phase[gc], &s1, &c1); }
    if (MODE == 2) { __sincosf(phase[gc], &s1, &c1); }
    if (MODE == 3 || MODE == 4) bv = biasp[gc];
#pragma unroll
    for (int m = 0; m < 4; ++m) {
#pragma unroll
      for (int j = 0; j < 4; ++j) {
        const int gr = row0 + m * 16 + l4 * 4 + j;
        const float v = acc[m][n][j];
        if (MODE == 0) {
          const int bI = gr >> 10, sI = gr & 1023;
          const int hI = gc >> 6, dI = gc & 63;
          out0[(((size_t)(bI * H_N + hI)) * S_N + sI) * D_N + dI] = f2bf(v);
        } else if (MODE == 1) {
          const int bI = gr >> 10, sI = gr & 1023;
          const int hI = gc >> 6, dI = gc & 63;
          const size_t idx = (((size_t)(bI * H_N + hI)) * S_N + sI) * D_N + dI;
          out0[idx] = f2bf(v * c1 * 0.125f);
          out1[idx] = f2bf(v * s1 * 0.125f);
        } else if (MODE == 2) {
          const int bI = gr >> 10, sI = gr & 1023;
          const int hI = gc >> 6, dI = gc & 63;
          const size_t idx = (((size_t)(bI * H_N + hI)) * D_N + dI) * S_N + sI;
          out0[idx] = f2bf(v * c1);
          out1[idx] = f2bf(v * s1);
        } else if (MODE == 3) {
          out0[(size_t)gr * F_N + gc] = f2bf(fmaxf(v + bv, 0.f));
        } else if (MODE == 4) {
          fout[(size_t)gr * E_N + gc] = v + bv;
        }
      }
    }
  }
}

// ---------------- fused complex flash attention ----------------
// Per block: (b,h) and 128 q-rows. 4 waves x 32 q-cols each (swapped-operand MFMA).
// S^T[t][q] = sum_d Kc[t][d]*Q[q][d]  (re) / Ks (im); online complex softmax;
// N^T[d][q] += VcT@Pre + (-VsT)@Pim (re), VsT@Pre + VcT@Pim (im).
__global__ __launch_bounds__(256) void attn_kernel(
    const u16* __restrict__ Qg, const u16* __restrict__ Kcg,
    const u16* __restrict__ Ksg, const u16* __restrict__ Vcg,
    const u16* __restrict__ Vsg, float* __restrict__ outp) {
  __shared__ u16 KcS[32 * 64], KsS[32 * 64];
  __shared__ u16 VcS[64 * 32], VsS[64 * 32], VnS[64 * 32];
  __shared__ u16 PreS[128 * 32], PimS[128 * 32];

  const int tid = threadIdx.x;
  const int lane = tid & 63, wv = tid >> 6;
  const int l15 = lane & 15, l4 = lane >> 4;
  const int qt = blockIdx.x, hh = blockIdx.y, bb = blockIdx.z;
  const size_t hoff = ((size_t)(bb * H_N + hh)) * S_N * D_N;
  const u16* Kc = Kcg + hoff;
  const u16* Ks = Ksg + hoff;
  const u16* Vc = Vcg + hoff;
  const u16* Vs = Vsg + hoff;

  u16x8 qf[2][2];
#pragma unroll
  for (int qb = 0; qb < 2; ++qb)
#pragma unroll
    for (int ks = 0; ks < 2; ++ks)
      qf[qb][ks] = *(const u16x8*)(Qg + hoff +
          (size_t)(qt * 128 + wv * 32 + qb * 16 + l15) * D_N + ks * 32 + l4 * 8);

  f32x4 z4 = {0.f, 0.f, 0.f, 0.f};
  f32x4 Nre[2][4], Nim[2][4];
#pragma unroll
  for (int qb = 0; qb < 2; ++qb)
#pragma unroll
    for (int db = 0; db < 4; ++db) { Nre[qb][db] = z4; Nim[qb][db] = z4; }
  float mm[2] = {-1e30f, -1e30f};
  float zre[2] = {0.f, 0.f}, zim[2] = {0.f, 0.f};

  const int rk = tid >> 3, ck = tid & 7;
  const int offk = (rk * 128 + ck * 16) ^ ((rk & 7) << 4);
  const int rv = tid >> 2, cv = tid & 3;
  const int offv = (rv * 64 + cv * 16) ^ (((rv >> 1) & 3) << 4);
  const u32x4 smask = {0x80008000u, 0x80008000u, 0x80008000u, 0x80008000u};

  for (int kt = 0; kt < 32; ++kt) {
    *(u32x4*)((char*)KcS + offk) = *(const u32x4*)(Kc + (size_t)(kt * 32 + rk) * 64 + ck * 8);
    *(u32x4*)((char*)KsS + offk) = *(const u32x4*)(Ks + (size_t)(kt * 32 + rk) * 64 + ck * 8);
    u32x4 vcv = *(const u32x4*)(Vc + (size_t)rv * S_N + kt * 32 + cv * 8);
    u32x4 vsv = *(const u32x4*)(Vs + (size_t)rv * S_N + kt * 32 + cv * 8);
    *(u32x4*)((char*)VcS + offv) = vcv;
    *(u32x4*)((char*)VsS + offv) = vsv;
    *(u32x4*)((char*)VnS + offv) = vsv ^ smask;
    __syncthreads();

    f32x4 sre[2][2], sim[2][2];
#pragma unroll
    for (int qb = 0; qb < 2; ++qb)
#pragma unroll
      for (int tb = 0; tb < 2; ++tb) { sre[qb][tb] = z4; sim[qb][tb] = z4; }
#pragma unroll
    for (int tb = 0; tb < 2; ++tb)
#pragma unroll
      for (int ks = 0; ks < 2; ++ks) {
        int row = tb * 16 + l15;
        int off = (row * 128 + ks * 64 + (l4 << 4)) ^ ((row & 7) << 4);
        u16x8 akc = *(const u16x8*)((const char*)KcS + off);
        u16x8 aks = *(const u16x8*)((const char*)KsS + off);
#pragma unroll
        for (int qb = 0; qb < 2; ++qb) {
          sre[qb][tb] = mfma16(akc, qf[qb][ks], sre[qb][tb]);
          sim[qb][tb] = mfma16(aks, qf[qb][ks], sim[qb][tb]);
        }
      }

#pragma unroll
    for (int qb = 0; qb < 2; ++qb) {
      float tm = -1e30f;
#pragma unroll
      for (int tb = 0; tb < 2; ++tb)
#pragma unroll
        for (int j = 0; j < 4; ++j) tm = fmaxf(tm, sre[qb][tb][j]);
      tm = fmaxf(tm, __shfl_xor(tm, 16));
      tm = fmaxf(tm, __shfl_xor(tm, 32));
      const float mn = fmaxf(mm[qb], tm);
      const float sc = __expf(mm[qb] - mn);
      mm[qb] = mn;
      zre[qb] *= sc; zim[qb] *= sc;
#pragma unroll
      for (int db = 0; db < 4; ++db) { Nre[qb][db] *= sc; Nim[qb][db] *= sc; }
      const int qrow = wv * 32 + qb * 16 + l15;
#pragma unroll
      for (int tb = 0; tb < 2; ++tb) {
        u16x4 pr4, pi4;
#pragma unroll
        for (int j = 0; j < 4; ++j) {
          const float e = __expf(sre[qb][tb][j] - mn);
          float si, co;
          __sincosf(sim[qb][tb][j], &si, &co);
          const u16 prb = f2bf(e * co);
          const u16 pib = f2bf(e * si);
          zre[qb] += bf2f(prb);
          zim[qb] += bf2f(pib);
          pr4[j] = prb; pi4[j] = pib;
        }
        const int offp = (qrow * 64 + tb * 32 + l4 * 8) ^ (((qrow >> 1) & 3) << 4);
        *(u16x4*)((char*)PreS + offp) = pr4;
        *(u16x4*)((char*)PimS + offp) = pi4;
      }
    }

    // PV (P tiles are wave-private: no barrier needed between write and read)
    u16x8 bre[2], bim[2];
#pragma unroll
    for (int qb = 0; qb < 2; ++qb) {
      const int prow = wv * 32 + qb * 16 + l15;
      const int offp = (prow * 64 + (l4 << 4)) ^ (((prow >> 1) & 3) << 4);
      bre[qb] = *(const u16x8*)((const char*)PreS + offp);
      bim[qb] = *(const u16x8*)((const char*)PimS + offp);
    }
#pragma unroll
    for (int db = 0; db < 4; ++db) {
      const int vrow = db * 16 + l15;
      const int offv2 = (vrow * 64 + (l4 << 4)) ^ (((vrow >> 1) & 3) << 4);
      u16x8 avc = *(const u16x8*)((const char*)VcS + offv2);
      u16x8 avs = *(const u16x8*)((const char*)VsS + offv2);
      u16x8 avn = *(const u16x8*)((const char*)VnS + offv2);
#pragma unroll
      for (int qb = 0; qb < 2; ++qb) {
        Nre[qb][db] = mfma16(avc, bre[qb], Nre[qb][db]);
        Nre[qb][db] = mfma16(avn, bim[qb], Nre[qb][db]);
        Nim[qb][db] = mfma16(avs, bre[qb], Nim[qb][db]);
        Nim[qb][db] = mfma16(avc, bim[qb], Nim[qb][db]);
      }
    }
    __syncthreads();
  }

#pragma unroll
  for (int qb = 0; qb < 2; ++qb) {
    float zr = zre[qb], zi = zim[qb];
    zr += __shfl_xor(zr, 16); zr += __shfl_xor(zr, 32);
    zi += __shfl_xor(zi, 16); zi += __shfl_xor(zi, 32);
    const float inv = 1.f / (zr * zr + zi * zi);
    const int q = qt * 128 + wv * 32 + qb * 16 + l15;
    float* orow = outp + ((size_t)(bb * S_N + q)) * E_N + hh * 64;
#pragma unroll
    for (int db = 0; db < 4; ++db)
#pragma unroll
      for (int j = 0; j < 4; ++j) {
        const int d = db * 16 + l4 * 4 + j;
        orow[d] = (Nre[qb][db][j] * zr + Nim[qb][db][j] * zi) * inv;
      }
  }
}

// ---------------- residual add + LayerNorm ----------------
__global__ __launch_bounds__(256) void add_ln_kernel(
    const float* __restrict__ a, const float* __restrict__ r,
    const float* __restrict__ g, const float* __restrict__ be,
    float* __restrict__ outf, u16* __restrict__ outb) {
  const int tid = threadIdx.x;
  const int row = blockIdx.x;
  const int lane = tid & 63, wv = tid >> 6;
  const float4 va = ((const float4*)(a + (size_t)row * 1024))[tid];
  const float4 vr = ((const float4*)(r + (size_t)row * 1024))[tid];
  float4 v;
  v.x = va.x + vr.x; v.y = va.y + vr.y; v.z = va.z + vr.z; v.w = va.w + vr.w;
  float s = v.x + v.y + v.z + v.w;
#pragma unroll
  for (int m = 1; m < 64; m <<= 1) s += __shfl_xor(s, m);
  __shared__ float red[8];
  if (lane == 0) red[wv] = s;
  __syncthreads();
  s = red[0] + red[1] + red[2] + red[3];
  const float mu = s * (1.f / 1024.f);
  float4 xc;
  xc.x = v.x - mu; xc.y = v.y - mu; xc.z = v.z - mu; xc.w = v.w - mu;
  float q = xc.x * xc.x + xc.y * xc.y + xc.z * xc.z + xc.w * xc.w;
#pragma unroll
  for (int m = 1; m < 64; m <<= 1) q += __shfl_xor(q, m);
  if (lane == 0) red[4 + wv] = q;
  __syncthreads();
  q = red[4] + red[5] + red[6] + red[7];
  const float rs = rsqrtf(q * (1.f / 1024.f) + 1e-5f);
  const float4 gg = ((const float4*)g)[tid];
  const float4 bb4 = ((const float4*)be)[tid];
  float4 o;
  o.x = xc.x * rs * gg.x + bb4.x;
  o.y = xc.y * rs * gg.y + bb4.y;
  o.z = xc.z * rs * gg.z + bb4.z;
  o.w = xc.w * rs * gg.w + bb4.w;
  if (outf) ((float4*)(outf + (size_t)row * 1024))[tid] = o;
  if (outb) {
    u16x4 ob;
    ob[0] = f2bf(o.x); ob[1] = f2bf(o.y); ob[2] = f2bf(o.z); ob[3] = f2bf(o.w);
    *(u16x4*)(outb + (size_t)row * 1024 + tid * 4) = ob;
  }
}

extern "C" void kernel_launch(void* const* d_in, const int* in_sizes, int n_in,
                              void* d_out, int out_size, void* d_ws, size_t ws_size,
                              hipStream_t stream) {
  (void)in_sizes; (void)n_in; (void)out_size; (void)ws_size;
  const float* x = (const float*)d_in[0];
  const float* wq = (const float*)d_in[1];
  const float* wk = (const float*)d_in[2];
  const float* wvp = (const float*)d_in[3];
  const float* phase = (const float*)d_in[4];
  const float* ln1g = (const float*)d_in[5];
  const float* ln1b = (const float*)d_in[6];
  const float* ln2g = (const float*)d_in[7];
  const float* ln2b = (const float*)d_in[8];
  const float* w1 = (const float*)d_in[9];
  const float* b1 = (const float*)d_in[10];
  const float* w2 = (const float*)d_in[11];
  const float* b2 = (const float*)d_in[12];
  float* outp = (float*)d_out;

  char* p = (char*)d_ws;
  auto alloc = [&](size_t n) -> char* {
    char* q = p;
    p += (n + 255) & ~(size_t)255;
    return q;
  };
  const size_t TOKE = (size_t)NTOK * E_N;  // 4M elements
  u16* xb = (u16*)alloc(TOKE * 2);
  u16* wqb = (u16*)alloc((size_t)E_N * E_N * 2);
  u16* wkb = (u16*)alloc((size_t)E_N * E_N * 2);
  u16* wvb = (u16*)alloc((size_t)E_N * E_N * 2);
  u16* w1b = (u16*)alloc((size_t)F_N * E_N * 2);
  u16* w2b = (u16*)alloc((size_t)E_N * F_N * 2);
  u16* Qp = (u16*)alloc(TOKE * 2);
  u16* Kcp = (u16*)alloc(TOKE * 2);
  u16* Ksp = (u16*)alloc(TOKE * 2);
  u16* Vcp = (u16*)alloc(TOKE * 2);
  u16* Vsp = (u16*)alloc(TOKE * 2);
  float* attn_o = (float*)alloc(TOKE * 4);
  float* x1f = (float*)alloc(TOKE * 4);
  // buffer reuse (lifetimes disjoint):
  u16* x1b = xb;        // xb dead after V projection
  u16* hb = Qp;         // Q/Kc/Ks/Vc (32MB) dead after attention
  float* ffn = attn_o;  // attn_o dead after LN1

  dim3 blk(256);
  cvt_kernel<<<dim3((int)(TOKE / 1024)), blk, 0, stream>>>(x, xb, (int)(TOKE / 4));
  cvt_kernel<<<dim3(E_N * E_N / 1024), blk, 0, stream>>>(wq, wqb, E_N * E_N / 4);
  cvt_kernel<<<dim3(E_N * E_N / 1024), blk, 0, stream>>>(wk, wkb, E_N * E_N / 4);
  cvt_kernel<<<dim3(E_N * E_N / 1024), blk, 0, stream>>>(wvp, wvb, E_N * E_N / 4);
  cvt_kernel<<<dim3(F_N * E_N / 1024), blk, 0, stream>>>(w1, w1b, F_N * E_N / 4);
  cvt_kernel<<<dim3(E_N * F_N / 1024), blk, 0, stream>>>(w2, w2b, E_N * F_N / 4);

  dim3 gq(E_N / 128, NTOK / 128);
  gemm_bt<0><<<gq, blk, 0, stream>>>(xb, wqb, NTOK, E_N, E_N, nullptr, Qp, nullptr, phase, nullptr);
  gemm_bt<1><<<gq, blk, 0, stream>>>(xb, wkb, NTOK, E_N, E_N, nullptr, Kcp, Ksp, phase, nullptr);
  gemm_bt<2><<<gq, blk, 0, stream>>>(xb, wvb, NTOK, E_N, E_N, nullptr, Vcp, Vsp, phase, nullptr);

  attn_kernel<<<dim3(S_N / 128, H_N, B_N), blk, 0, stream>>>(Qp, Kcp, Ksp, Vcp, Vsp, attn_o);

  add_ln_kernel<<<dim3(NTOK), blk, 0, stream>>>(x, attn_o, ln1g, ln1b, x1f, x1b);

  gemm_bt<3><<<dim3(F_N / 128, NTOK / 128), blk, 0, stream>>>(
      x1b, w1b, NTOK, F_N, E_N, nullptr, hb, nullptr, nullptr, b1);
  gemm_bt<4><<<dim3(E_N / 128, NTOK / 128), blk, 0, stream>>>(
      hb, w2b, NTOK, E_N, F_N, ffn, nullptr, nullptr, nullptr, b2);

  add_ln_kernel<<<dim3(NTOK), blk, 0, stream>>>(x1f, ffn, ln2g, ln2b, outp, nullptr);
}

// Round 2
// 286.660 us; speedup vs baseline: 1.1418x; 1.1418x over previous
//
#include <hip/hip_runtime.h>

typedef unsigned short u16;
typedef unsigned int u32;
typedef u16 u16x4 __attribute__((ext_vector_type(4)));
typedef u16 u16x8 __attribute__((ext_vector_type(8)));
typedef u32 u32x2 __attribute__((ext_vector_type(2)));
typedef u32 u32x4 __attribute__((ext_vector_type(4)));
typedef float f32x4 __attribute__((ext_vector_type(4)));
typedef __bf16 bf16x8 __attribute__((ext_vector_type(8)));

#define B_N 4
#define S_N 1024
#define E_N 1024
#define H_N 16
#define D_N 64
#define F_N 4096
#define NTOK 4096

// Kc scale folds 1/sqrt(D)=0.125 and log2(e) (softmax done in exp2 domain).
// Ks scale folds 0.125 and 1/(2*pi) (v_sin/v_cos take revolutions).
#define SCK 0.18033688011112042f
#define SSK 0.01989436788648692f

static __device__ __forceinline__ u16 f2bf(float f) {
  u32 u = __builtin_bit_cast(u32, f);
  return (u16)((u + 0x7fffu + ((u >> 16) & 1u)) >> 16);
}
static __device__ __forceinline__ f32x4 mfma16(u16x8 a, u16x8 b, f32x4 c) {
  return __builtin_amdgcn_mfma_f32_16x16x32_bf16(
      __builtin_bit_cast(bf16x8, a), __builtin_bit_cast(bf16x8, b), c, 0, 0, 0);
}
static __device__ __forceinline__ float exp2_hw(float x) {
  float r; asm("v_exp_f32 %0, %1" : "=v"(r) : "v"(x)); return r;
}
static __device__ __forceinline__ float sin_hw(float x) {
  float r; asm("v_sin_f32 %0, %1" : "=v"(r) : "v"(x)); return r;
}
static __device__ __forceinline__ float cos_hw(float x) {
  float r; asm("v_cos_f32 %0, %1" : "=v"(r) : "v"(x)); return r;
}
static __device__ __forceinline__ u32 cvtpk(float lo, float hi) {
  u32 r; asm("v_cvt_pk_bf16_f32 %0, %1, %2" : "=v"(r) : "v"(lo), "v"(hi)); return r;
}
#define GLOAD16(gp, lp)                                              \
  __builtin_amdgcn_global_load_lds(                                  \
      (const __attribute__((address_space(1))) void*)(gp),           \
      (__attribute__((address_space(3))) void*)(lp), 16, 0, 0)

// ---------------- f32 -> bf16 conversion ----------------
__global__ __launch_bounds__(256) void cvt_kernel(const float* __restrict__ in,
                                                  u16* __restrict__ out, int n4) {
  int i = blockIdx.x * 256 + threadIdx.x;
  if (i < n4) {
    float4 v = ((const float4*)in)[i];
    u16x4 o;
    o[0] = f2bf(v.x); o[1] = f2bf(v.y); o[2] = f2bf(v.z); o[3] = f2bf(v.w);
    ((u16x4*)out)[i] = o;
  }
}

// ---------------- GEMM: C[M,N] = A[M,K] @ B[N,K]^T (bf16 in, f32 acc) ----------------
// MODE 5: fused QKV projection (bx regions: 0-7 Q, 8-15 K, 16-23 V)
// MODE 3: FFN1  -> o0[r,n] = bf16(relu(v + bias[n]))
// MODE 4: FFN2  -> fout[r,n] = v + bias[n]
template <int MODE>
__global__ __launch_bounds__(256) void gemm_bt(
    const u16* __restrict__ A, const u16* __restrict__ B0,
    const u16* __restrict__ B1, const u16* __restrict__ B2, int K,
    float* __restrict__ fout, u16* __restrict__ o0, u16* __restrict__ o1,
    u16* __restrict__ o2, u16* __restrict__ o3, u16* __restrict__ o4,
    const float* __restrict__ phase, const float* __restrict__ biasp) {
  __shared__ u16 As[2][128 * 32];
  __shared__ u16 Bs[2][128 * 32];
  const int tid = threadIdx.x;
  const int lane = tid & 63;
  const int wv = tid >> 6;
  const int wr = wv >> 1, wc = wv & 1;
  const int bx = blockIdx.x, by = blockIdx.y;
  const int l15 = lane & 15, l4 = lane >> 4;

  int bxl = bx;
  const u16* Bsrc = B0;
  if constexpr (MODE == 5) {
    const int region = bx >> 3;
    bxl = bx & 7;
    Bsrc = (region == 0) ? B0 : (region == 1) ? B1 : B2;
  }
  const u16* Ab = A + (size_t)(by * 128) * K;
  const u16* Bb = Bsrc + (size_t)(bxl * 128) * K;

  f32x4 z4 = {0.f, 0.f, 0.f, 0.f};
  f32x4 acc[4][4];
#pragma unroll
  for (int m = 0; m < 4; ++m)
#pragma unroll
    for (int n = 0; n < 4; ++n) acc[m][n] = z4;

  // stage one 128x32 K-slab of A and B into LDS buffer `bufi` via
  // global_load_lds width-16; LDS is written linearly (wave-uniform base +
  // lane*16), the XOR swizzle is applied by permuting the SOURCE chunk.
  auto stage = [&](int bufi, int kt) {
#pragma unroll
    for (int i = 0; i < 2; ++i) {
      const int ci = wv * 2 + i;           // 1KB chunk per wave-call
      const int q = ci * 64 + lane;        // 16B chunk id 0..511
      const int row = q >> 2;
      const int cs = (q & 3) ^ ((row >> 1) & 3);
      const size_t goff = (size_t)row * K + kt * 32 + cs * 8;
      GLOAD16(Ab + goff, (char*)As[bufi] + ci * 1024);
      GLOAD16(Bb + goff, (char*)Bs[bufi] + ci * 1024);
    }
  };

  stage(0, 0);
  __syncthreads();

  const int KT = K >> 5;
  int cur = 0;
  for (int kt = 0; kt < KT; ++kt) {
    if (kt + 1 < KT) stage(cur ^ 1, kt + 1);
    u16x8 af[4], bf4[4];
#pragma unroll
    for (int m = 0; m < 4; ++m) {
      int row = wr * 64 + m * 16 + l15;
      int off = (row * 64 + (l4 << 4)) ^ (((row >> 1) & 3) << 4);
      af[m] = *(const u16x8*)((const char*)As[cur] + off);
    }
#pragma unroll
    for (int n = 0; n < 4; ++n) {
      int row = wc * 64 + n * 16 + l15;
      int off = (row * 64 + (l4 << 4)) ^ (((row >> 1) & 3) << 4);
      bf4[n] = *(const u16x8*)((const char*)Bs[cur] + off);
    }
    __builtin_amdgcn_s_setprio(1);
#pragma unroll
    for (int m = 0; m < 4; ++m)
#pragma unroll
      for (int n = 0; n < 4; ++n) acc[m][n] = mfma16(af[m], bf4[n], acc[m][n]);
    __builtin_amdgcn_s_setprio(0);
    __syncthreads();
    cur ^= 1;
  }

  // epilogue
  const int row0 = by * 128 + wr * 64;
  const int col0 = bxl * 128 + wc * 64;
  if constexpr (MODE == 5) {
    const int region = bx >> 3;
#pragma unroll
    for (int n = 0; n < 4; ++n) {
      const int gc = col0 + n * 16 + l15;
      const int hI = gc >> 6, dI = gc & 63;
      float c1 = 0.f, s1 = 0.f;
      if (region == 1) __sincosf(2.f * phase[gc], &s1, &c1);
      if (region == 2) __sincosf(phase[gc], &s1, &c1);
#pragma unroll
      for (int m = 0; m < 4; ++m)
#pragma unroll
        for (int j = 0; j < 4; ++j) {
          const int gr = row0 + m * 16 + l4 * 4 + j;
          const int bI = gr >> 10, sI = gr & 1023;
          const float v = acc[m][n][j];
          if (region == 0) {
            o0[(((size_t)(bI * H_N + hI)) * S_N + sI) * D_N + dI] = f2bf(v);
          } else if (region == 1) {
            const size_t idx = (((size_t)(bI * H_N + hI)) * S_N + sI) * D_N + dI;
            o1[idx] = f2bf(v * c1 * SCK);
            o2[idx] = f2bf(v * s1 * SSK);
          } else {
            const size_t idx = (((size_t)(bI * H_N + hI)) * D_N + dI) * S_N + sI;
            o3[idx] = f2bf(v * c1);
            o4[idx] = f2bf(v * s1);
          }
        }
    }
  } else {
#pragma unroll
    for (int n = 0; n < 4; ++n) {
      const int gc = col0 + n * 16 + l15;
      const float bv = biasp[gc];
#pragma unroll
      for (int m = 0; m < 4; ++m)
#pragma unroll
        for (int j = 0; j < 4; ++j) {
          const int gr = row0 + m * 16 + l4 * 4 + j;
          const float v = acc[m][n][j];
          if constexpr (MODE == 3) {
            o0[(size_t)gr * F_N + gc] = f2bf(fmaxf(v + bv, 0.f));
          } else {
            fout[(size_t)gr * E_N + gc] = v + bv;
          }
        }
    }
  }
}

// ---------------- fused complex flash attention ----------------
// 512 threads = 8 waves, each owning 16 q-cols of a 128-q block; KV staged
// in 64-wide tiles (reg-prefetched), processed as two 32-t sub-steps.
// Scores in exp2 domain (log2e folded into Kc), imag in revolutions
// (1/2pi folded into Ks). Defer-max rescale (THR=8 log2 units).
__global__ __launch_bounds__(512, 4) void attn_kernel(
    const u16* __restrict__ Qg, const u16* __restrict__ Kcg,
    const u16* __restrict__ Ksg, const u16* __restrict__ Vcg,
    const u16* __restrict__ Vsg, float* __restrict__ outp) {
  __shared__ u16 KcS[64 * 64], KsS[64 * 64];
  __shared__ u16 VcS[64 * 64], VsS[64 * 64], VnS[64 * 64];
  __shared__ u16 PreS[128 * 32], PimS[128 * 32];

  const int tid = threadIdx.x;
  const int lane = tid & 63, wv = tid >> 6;
  const int l15 = lane & 15, l4 = lane >> 4;
  const int qt = blockIdx.x, hh = blockIdx.y, bb = blockIdx.z;
  const size_t hoff = ((size_t)(bb * H_N + hh)) * (size_t)(S_N * D_N);
  const u16* Kc = Kcg + hoff;
  const u16* Ks = Ksg + hoff;
  const u16* Vc = Vcg + hoff;
  const u16* Vs = Vsg + hoff;
  const int qrow = wv * 16 + l15;

  u16x8 qf[2];
#pragma unroll
  for (int ks = 0; ks < 2; ++ks)
    qf[ks] = *(const u16x8*)(Qg + hoff + (size_t)(qt * 128 + qrow) * D_N + ks * 32 + l4 * 8);

  f32x4 z4 = {0.f, 0.f, 0.f, 0.f};
  f32x4 Nre[4], Nim[4];
#pragma unroll
  for (int db = 0; db < 4; ++db) { Nre[db] = z4; Nim[db] = z4; }
  float mm = -1e30f, zre = 0.f, zim = 0.f;

  const int srow = tid >> 3, sc16 = tid & 7;
  const int skoff = (srow * 128 + sc16 * 16) ^ ((srow & 7) << 4);
  const u32x4 smask = {0x80008000u, 0x80008000u, 0x80008000u, 0x80008000u};

  // prefetch tile 0
  u32x4 rkc = *(const u32x4*)(Kc + (size_t)srow * 64 + sc16 * 8);
  u32x4 rks = *(const u32x4*)(Ks + (size_t)srow * 64 + sc16 * 8);
  u32x4 rvc = *(const u32x4*)(Vc + (size_t)srow * S_N + sc16 * 8);
  u32x4 rvs = *(const u32x4*)(Vs + (size_t)srow * S_N + sc16 * 8);

  for (int kt = 0; kt < 16; ++kt) {
    *(u32x4*)((char*)KcS + skoff) = rkc;
    *(u32x4*)((char*)KsS + skoff) = rks;
    *(u32x4*)((char*)VcS + skoff) = rvc;
    *(u32x4*)((char*)VsS + skoff) = rvs;
    *(u32x4*)((char*)VnS + skoff) = rvs ^ smask;
    if (kt < 15) {  // T14: issue next-tile loads under this tile's compute
      rkc = *(const u32x4*)(Kc + (size_t)((kt + 1) * 64 + srow) * 64 + sc16 * 8);
      rks = *(const u32x4*)(Ks + (size_t)((kt + 1) * 64 + srow) * 64 + sc16 * 8);
      rvc = *(const u32x4*)(Vc + (size_t)srow * S_N + (kt + 1) * 64 + sc16 * 8);
      rvs = *(const u32x4*)(Vs + (size_t)srow * S_N + (kt + 1) * 64 + sc16 * 8);
    }
    __syncthreads();

#pragma unroll
    for (int ts = 0; ts < 2; ++ts) {
      f32x4 sre[2], sim[2];
      sre[0] = z4; sre[1] = z4; sim[0] = z4; sim[1] = z4;
      __builtin_amdgcn_s_setprio(1);
#pragma unroll
      for (int tb = 0; tb < 2; ++tb) {
        const int trow = ts * 32 + tb * 16 + l15;
#pragma unroll
        for (int ks = 0; ks < 2; ++ks) {
          const int off = (trow * 128 + ks * 64 + (l4 << 4)) ^ ((trow & 7) << 4);
          u16x8 akc = *(const u16x8*)((const char*)KcS + off);
          u16x8 aks = *(const u16x8*)((const char*)KsS + off);
          sre[tb] = mfma16(akc, qf[ks], sre[tb]);
          sim[tb] = mfma16(aks, qf[ks], sim[tb]);
        }
      }
      __builtin_amdgcn_s_setprio(0);

      float tm = fmaxf(fmaxf(fmaxf(sre[0][0], sre[0][1]), fmaxf(sre[0][2], sre[0][3])),
                       fmaxf(fmaxf(sre[1][0], sre[1][1]), fmaxf(sre[1][2], sre[1][3])));
      tm = fmaxf(tm, __shfl_xor(tm, 16));
      tm = fmaxf(tm, __shfl_xor(tm, 32));
      if (__ballot(tm > mm + 8.f) != 0ull) {
        const float mn = fmaxf(mm, tm);
        const float sc = exp2_hw(mm - mn);
        mm = mn;
        zre *= sc; zim *= sc;
#pragma unroll
        for (int db = 0; db < 4; ++db) { Nre[db] *= sc; Nim[db] *= sc; }
      }

#pragma unroll
      for (int tb = 0; tb < 2; ++tb) {
        float pc[4], ps[4];
#pragma unroll
        for (int j = 0; j < 4; ++j) {
          const float e = exp2_hw(sre[tb][j] - mm);
          const float sn = sin_hw(sim[tb][j]);
          const float cs = cos_hw(sim[tb][j]);
          pc[j] = e * cs; ps[j] = e * sn;
        }
        zre += (pc[0] + pc[1]) + (pc[2] + pc[3]);
        zim += (ps[0] + ps[1]) + (ps[2] + ps[3]);
        u32x2 wre = {cvtpk(pc[0], pc[1]), cvtpk(pc[2], pc[3])};
        u32x2 wim = {cvtpk(ps[0], ps[1]), cvtpk(ps[2], ps[3])};
        const int offp = (qrow * 64 + tb * 32 + l4 * 8) ^ (((qrow >> 1) & 3) << 4);
        *(u32x2*)((char*)PreS + offp) = wre;
        *(u32x2*)((char*)PimS + offp) = wim;
      }

      // PV: P tiles are wave-private (rows wv*16..+16), no barrier needed.
      const int offp2 = (qrow * 64 + (l4 << 4)) ^ (((qrow >> 1) & 3) << 4);
      u16x8 bre = *(const u16x8*)((const char*)PreS + offp2);
      u16x8 bim = *(const u16x8*)((const char*)PimS + offp2);
      __builtin_amdgcn_s_setprio(1);
#pragma unroll
      for (int db = 0; db < 4; ++db) {
        const int vrow = db * 16 + l15;
        const int offv = (vrow * 128 + ts * 64 + (l4 << 4)) ^ ((vrow & 7) << 4);
        u16x8 avc = *(const u16x8*)((const char*)VcS + offv);
        u16x8 avs = *(const u16x8*)((const char*)VsS + offv);
        u16x8 avn = *(const u16x8*)((const char*)VnS + offv);
        Nre[db] = mfma16(avc, bre, Nre[db]);
        Nre[db] = mfma16(avn, bim, Nre[db]);
        Nim[db] = mfma16(avs, bre, Nim[db]);
        Nim[db] = mfma16(avc, bim, Nim[db]);
      }
      __builtin_amdgcn_s_setprio(0);
    }
    __syncthreads();
  }

  float zr = zre, zi = zim;
  zr += __shfl_xor(zr, 16); zr += __shfl_xor(zr, 32);
  zi += __shfl_xor(zi, 16); zi += __shfl_xor(zi, 32);
  const float inv = 1.f / (zr * zr + zi * zi);
  const int q = qt * 128 + qrow;
  float* orow = outp + ((size_t)(bb * S_N + q)) * E_N + hh * 64;
#pragma unroll
  for (int db = 0; db < 4; ++db) {
    float4 o;
    o.x = (Nre[db][0] * zr + Nim[db][0] * zi) * inv;
    o.y = (Nre[db][1] * zr + Nim[db][1] * zi) * inv;
    o.z = (Nre[db][2] * zr + Nim[db][2] * zi) * inv;
    o.w = (Nre[db][3] * zr + Nim[db][3] * zi) * inv;
    *(float4*)(orow + db * 16 + l4 * 4) = o;
  }
}

// ---------------- residual add + LayerNorm ----------------
__global__ __launch_bounds__(256) void add_ln_kernel(
    const float* __restrict__ a, const float* __restrict__ r,
    const float* __restrict__ g, const float* __restrict__ be,
    float* __restrict__ outf, u16* __restrict__ outb) {
  const int tid = threadIdx.x;
  const int row = blockIdx.x;
  const int lane = tid & 63, wv = tid >> 6;
  const float4 va = ((const float4*)(a + (size_t)row * 1024))[tid];
  const float4 vr = ((const float4*)(r + (size_t)row * 1024))[tid];
  float4 v;
  v.x = va.x + vr.x; v.y = va.y + vr.y; v.z = va.z + vr.z; v.w = va.w + vr.w;
  float s = v.x + v.y + v.z + v.w;
#pragma unroll
  for (int m = 1; m < 64; m <<= 1) s += __shfl_xor(s, m);
  __shared__ float red[8];
  if (lane == 0) red[wv] = s;
  __syncthreads();
  s = red[0] + red[1] + red[2] + red[3];
  const float mu = s * (1.f / 1024.f);
  float4 xc;
  xc.x = v.x - mu; xc.y = v.y - mu; xc.z = v.z - mu; xc.w = v.w - mu;
  float q = xc.x * xc.x + xc.y * xc.y + xc.z * xc.z + xc.w * xc.w;
#pragma unroll
  for (int m = 1; m < 64; m <<= 1) q += __shfl_xor(q, m);
  if (lane == 0) red[4 + wv] = q;
  __syncthreads();
  q = red[4] + red[5] + red[6] + red[7];
  const float rs = rsqrtf(q * (1.f / 1024.f) + 1e-5f);
  const float4 gg = ((const float4*)g)[tid];
  const float4 bb4 = ((const float4*)be)[tid];
  float4 o;
  o.x = xc.x * rs * gg.x + bb4.x;
  o.y = xc.y * rs * gg.y + bb4.y;
  o.z = xc.z * rs * gg.z + bb4.z;
  o.w = xc.w * rs * gg.w + bb4.w;
  if (outf) ((float4*)(outf + (size_t)row * 1024))[tid] = o;
  if (outb) {
    u16x4 ob;
    ob[0] = f2bf(o.x); ob[1] = f2bf(o.y); ob[2] = f2bf(o.z); ob[3] = f2bf(o.w);
    *(u16x4*)(outb + (size_t)row * 1024 + tid * 4) = ob;
  }
}

extern "C" void kernel_launch(void* const* d_in, const int* in_sizes, int n_in,
                              void* d_out, int out_size, void* d_ws, size_t ws_size,
                              hipStream_t stream) {
  (void)in_sizes; (void)n_in; (void)out_size; (void)ws_size;
  const float* x = (const float*)d_in[0];
  const float* wq = (const float*)d_in[1];
  const float* wk = (const float*)d_in[2];
  const float* wvp = (const float*)d_in[3];
  const float* phase = (const float*)d_in[4];
  const float* ln1g = (const float*)d_in[5];
  const float* ln1b = (const float*)d_in[6];
  const float* ln2g = (const float*)d_in[7];
  const float* ln2b = (const float*)d_in[8];
  const float* w1 = (const float*)d_in[9];
  const float* b1 = (const float*)d_in[10];
  const float* w2 = (const float*)d_in[11];
  const float* b2 = (const float*)d_in[12];
  float* outp = (float*)d_out;

  char* p = (char*)d_ws;
  auto alloc = [&](size_t n) -> char* {
    char* q = p;
    p += (n + 255) & ~(size_t)255;
    return q;
  };
  const size_t TOKE = (size_t)NTOK * E_N;  // 4M elements
  u16* xb = (u16*)alloc(TOKE * 2);
  u16* wqb = (u16*)alloc((size_t)E_N * E_N * 2);
  u16* wkb = (u16*)alloc((size_t)E_N * E_N * 2);
  u16* wvb = (u16*)alloc((size_t)E_N * E_N * 2);
  u16* w1b = (u16*)alloc((size_t)F_N * E_N * 2);
  u16* w2b = (u16*)alloc((size_t)E_N * F_N * 2);
  u16* Qp = (u16*)alloc(TOKE * 2);
  u16* Kcp = (u16*)alloc(TOKE * 2);
  u16* Ksp = (u16*)alloc(TOKE * 2);
  u16* Vcp = (u16*)alloc(TOKE * 2);
  u16* Vsp = (u16*)alloc(TOKE * 2);
  float* attn_o = (float*)alloc(TOKE * 4);
  float* x1f = (float*)alloc(TOKE * 4);
  // buffer reuse (lifetimes disjoint):
  u16* x1b = xb;        // xb dead after QKV projection
  u16* hb = Qp;         // Q/Kc/Ks/Vc (32MB) dead after attention
  float* ffn = attn_o;  // attn_o dead after LN1

  dim3 blk(256);
  cvt_kernel<<<dim3((int)(TOKE / 1024)), blk, 0, stream>>>(x, xb, (int)(TOKE / 4));
  cvt_kernel<<<dim3(E_N * E_N / 1024), blk, 0, stream>>>(wq, wqb, E_N * E_N / 4);
  cvt_kernel<<<dim3(E_N * E_N / 1024), blk, 0, stream>>>(wk, wkb, E_N * E_N / 4);
  cvt_kernel<<<dim3(E_N * E_N / 1024), blk, 0, stream>>>(wvp, wvb, E_N * E_N / 4);
  cvt_kernel<<<dim3(F_N * E_N / 1024), blk, 0, stream>>>(w1, w1b, F_N * E_N / 4);
  cvt_kernel<<<dim3(E_N * F_N / 1024), blk, 0, stream>>>(w2, w2b, E_N * F_N / 4);

  gemm_bt<5><<<dim3(24, 32), blk, 0, stream>>>(
      xb, wqb, wkb, wvb, E_N, nullptr, Qp, Kcp, Ksp, Vcp, Vsp, phase, nullptr);

  attn_kernel<<<dim3(8, 16, 4), dim3(512), 0, stream>>>(Qp, Kcp, Ksp, Vcp, Vsp, attn_o);

  add_ln_kernel<<<dim3(NTOK), blk, 0, stream>>>(x, attn_o, ln1g, ln1b, x1f, x1b);

  gemm_bt<3><<<dim3(32, 32), blk, 0, stream>>>(
      x1b, w1b, nullptr, nullptr, E_N, nullptr, hb, nullptr, nullptr, nullptr,
      nullptr, nullptr, b1);
  gemm_bt<4><<<dim3(8, 32), blk, 0, stream>>>(
      hb, w2b, nullptr, nullptr, F_N, ffn, nullptr, nullptr, nullptr, nullptr,
      nullptr, nullptr, b2);

  add_ln_kernel<<<dim3(NTOK), blk, 0, stream>>>(x1f, ffn, ln2g, ln2b, outp, nullptr);
}

// Round 3
// 272.286 us; speedup vs baseline: 1.2021x; 1.0528x over previous
//
#include <hip/hip_runtime.h>

typedef unsigned short u16;
typedef unsigned int u32;
typedef u16 u16x4 __attribute__((ext_vector_type(4)));
typedef u16 u16x8 __attribute__((ext_vector_type(8)));
typedef u32 u32x2 __attribute__((ext_vector_type(2)));
typedef u32 u32x4 __attribute__((ext_vector_type(4)));
typedef float f32x4 __attribute__((ext_vector_type(4)));
typedef __bf16 bf16x8 __attribute__((ext_vector_type(8)));

#define B_N 4
#define S_N 1024
#define E_N 1024
#define H_N 16
#define D_N 64
#define F_N 4096
#define NTOK 4096

// Kc scale folds 1/sqrt(D)=0.125 and log2(e) (softmax done in exp2 domain).
// Ks scale folds 0.125 and 1/(2*pi) (v_sin/v_cos take revolutions).
#define SCK 0.18033688011112042f
#define SSK 0.01989436788648692f

static __device__ __forceinline__ u16 f2bf(float f) {
  u32 u = __builtin_bit_cast(u32, f);
  return (u16)((u + 0x7fffu + ((u >> 16) & 1u)) >> 16);
}
static __device__ __forceinline__ f32x4 mfma16(u16x8 a, u16x8 b, f32x4 c) {
  return __builtin_amdgcn_mfma_f32_16x16x32_bf16(
      __builtin_bit_cast(bf16x8, a), __builtin_bit_cast(bf16x8, b), c, 0, 0, 0);
}
static __device__ __forceinline__ float exp2_hw(float x) {
  float r; asm("v_exp_f32 %0, %1" : "=v"(r) : "v"(x)); return r;
}
static __device__ __forceinline__ float sin_hw(float x) {
  float r; asm("v_sin_f32 %0, %1" : "=v"(r) : "v"(x)); return r;
}
static __device__ __forceinline__ float cos_hw(float x) {
  float r; asm("v_cos_f32 %0, %1" : "=v"(r) : "v"(x)); return r;
}
static __device__ __forceinline__ u32 cvtpk(float lo, float hi) {
  u32 r; asm("v_cvt_pk_bf16_f32 %0, %1, %2" : "=v"(r) : "v"(lo), "v"(hi)); return r;
}
#define GLOAD16(gp, lp)                                              \
  __builtin_amdgcn_global_load_lds(                                  \
      (const __attribute__((address_space(1))) void*)(gp),           \
      (__attribute__((address_space(3))) void*)(lp), 16, 0, 0)

// ---------------- fused f32 -> bf16 conversion (6 segments in one launch) ----
__global__ __launch_bounds__(256) void cvt_all(
    const float* __restrict__ s0, u16* __restrict__ d0, int n0,
    const float* __restrict__ s1, u16* __restrict__ d1, int n1,
    const float* __restrict__ s2, u16* __restrict__ d2, int n2,
    const float* __restrict__ s3, u16* __restrict__ d3, int n3,
    const float* __restrict__ s4, u16* __restrict__ d4, int n4,
    const float* __restrict__ s5, u16* __restrict__ d5, int n5) {
  const int seg = blockIdx.y;
  const float* src; u16* dst; int n;
  switch (seg) {
    case 0: src = s0; dst = d0; n = n0; break;
    case 1: src = s1; dst = d1; n = n1; break;
    case 2: src = s2; dst = d2; n = n2; break;
    case 3: src = s3; dst = d3; n = n3; break;
    case 4: src = s4; dst = d4; n = n4; break;
    default: src = s5; dst = d5; n = n5; break;
  }
  int i = blockIdx.x * 256 + threadIdx.x;
  if (i < n) {
    float4 v = ((const float4*)src)[i];
    u16x4 o;
    o[0] = f2bf(v.x); o[1] = f2bf(v.y); o[2] = f2bf(v.z); o[3] = f2bf(v.w);
    ((u16x4*)dst)[i] = o;
  }
}

// ---------------- GEMM: C[M,N] = A[M,K] @ B[N,K]^T (bf16 in, f32 acc) ----------------
// MODE 5: fused QKV projection (bx regions: 0-7 Q, 8-15 K, 16-23 V), TN=128
// MODE 3: FFN1  -> o0[r,n] = bf16(relu(v + bias[n])), TN=128
// MODE 4: FFN2  -> fout[r,n] = v + bias[n], TN=64 (2 blocks/CU for occupancy)
template <int MODE, int TN>
__global__ __launch_bounds__(256) void gemm_bt(
    const u16* __restrict__ A, const u16* __restrict__ B0,
    const u16* __restrict__ B1, const u16* __restrict__ B2, int K,
    float* __restrict__ fout, u16* __restrict__ o0, u16* __restrict__ o1,
    u16* __restrict__ o2, u16* __restrict__ o3, u16* __restrict__ o4,
    const float* __restrict__ phase, const float* __restrict__ biasp) {
  __shared__ u16 As[2][128 * 32];
  __shared__ u16 Bs[2][TN * 32];
  const int tid = threadIdx.x;
  const int lane = tid & 63;
  const int wv = tid >> 6;
  const int wr = wv >> 1, wc = wv & 1;
  const int l15 = lane & 15, l4 = lane >> 4;
  constexpr int NB = TN / 32;  // 16-col fragments per wave

  // T1: bijective chunked XCD swizzle (all grids are multiples of 8 blocks).
  const int gx = gridDim.x;
  const int nwg = gx * gridDim.y;
  int lin = blockIdx.y * gx + blockIdx.x;
  lin = (lin & 7) * (nwg >> 3) + (lin >> 3);
  const int bx = lin % gx, by = lin / gx;

  int bxl = bx;
  const u16* Bsrc = B0;
  if constexpr (MODE == 5) {
    const int region = bx >> 3;
    bxl = bx & 7;
    Bsrc = (region == 0) ? B0 : (region == 1) ? B1 : B2;
  }
  const u16* Ab = A + (size_t)(by * 128) * K;
  const u16* Bb = Bsrc + (size_t)(bxl * TN) * K;

  f32x4 z4 = {0.f, 0.f, 0.f, 0.f};
  f32x4 acc[4][NB];
#pragma unroll
  for (int m = 0; m < 4; ++m)
#pragma unroll
    for (int n = 0; n < NB; ++n) acc[m][n] = z4;

  // stage one K-slab (A:128x32, B:TNx32) into LDS buffer `bufi` via
  // global_load_lds width-16; LDS written linearly, XOR swizzle applied by
  // permuting the SOURCE 16B-chunk column.
  auto stage = [&](int bufi, int kt) {
#pragma unroll
    for (int i = 0; i < 2; ++i) {
      const int ci = wv * 2 + i;
      const int q = ci * 64 + lane;
      const int row = q >> 2;
      const int cs = (q & 3) ^ ((row >> 1) & 3);
      GLOAD16(Ab + (size_t)row * K + kt * 32 + cs * 8, (char*)As[bufi] + ci * 1024);
    }
#pragma unroll
    for (int i = 0; i < TN / 64; ++i) {
      const int ci = wv * (TN / 64) + i;
      const int q = ci * 64 + lane;
      const int row = q >> 2;
      const int cs = (q & 3) ^ ((row >> 1) & 3);
      GLOAD16(Bb + (size_t)row * K + kt * 32 + cs * 8, (char*)Bs[bufi] + ci * 1024);
    }
  };

  stage(0, 0);
  __syncthreads();

  const int KT = K >> 5;
  int cur = 0;
  for (int kt = 0; kt < KT; ++kt) {
    if (kt + 1 < KT) stage(cur ^ 1, kt + 1);
    u16x8 af[4], bf4[NB];
#pragma unroll
    for (int m = 0; m < 4; ++m) {
      int row = wr * 64 + m * 16 + l15;
      int off = (row * 64 + (l4 << 4)) ^ (((row >> 1) & 3) << 4);
      af[m] = *(const u16x8*)((const char*)As[cur] + off);
    }
#pragma unroll
    for (int n = 0; n < NB; ++n) {
      int row = wc * (TN / 2) + n * 16 + l15;
      int off = (row * 64 + (l4 << 4)) ^ (((row >> 1) & 3) << 4);
      bf4[n] = *(const u16x8*)((const char*)Bs[cur] + off);
    }
    __builtin_amdgcn_s_setprio(1);
#pragma unroll
    for (int m = 0; m < 4; ++m)
#pragma unroll
      for (int n = 0; n < NB; ++n) acc[m][n] = mfma16(af[m], bf4[n], acc[m][n]);
    __builtin_amdgcn_s_setprio(0);
    __syncthreads();
    cur ^= 1;
  }

  // epilogue
  const int row0 = by * 128 + wr * 64;
  const int col0 = bxl * TN + wc * (TN / 2);
  if constexpr (MODE == 5) {
    const int region = bx >> 3;
#pragma unroll
    for (int n = 0; n < NB; ++n) {
      const int gc = col0 + n * 16 + l15;
      const int hI = gc >> 6, dI = gc & 63;
      float c1 = 0.f, s1 = 0.f;
      if (region == 1) __sincosf(2.f * phase[gc], &s1, &c1);
      if (region == 2) __sincosf(phase[gc], &s1, &c1);
#pragma unroll
      for (int m = 0; m < 4; ++m)
#pragma unroll
        for (int j = 0; j < 4; ++j) {
          const int gr = row0 + m * 16 + l4 * 4 + j;
          const int bI = gr >> 10, sI = gr & 1023;
          const float v = acc[m][n][j];
          if (region == 0) {
            o0[(((size_t)(bI * H_N + hI)) * S_N + sI) * D_N + dI] = f2bf(v);
          } else if (region == 1) {
            const size_t idx = (((size_t)(bI * H_N + hI)) * S_N + sI) * D_N + dI;
            o1[idx] = f2bf(v * c1 * SCK);
            o2[idx] = f2bf(v * s1 * SSK);
          } else {
            const size_t idx = (((size_t)(bI * H_N + hI)) * D_N + dI) * S_N + sI;
            o3[idx] = f2bf(v * c1);
            o4[idx] = f2bf(v * s1);
          }
        }
    }
  } else {
#pragma unroll
    for (int n = 0; n < NB; ++n) {
      const int gc = col0 + n * 16 + l15;
      const float bv = biasp[gc];
#pragma unroll
      for (int m = 0; m < 4; ++m)
#pragma unroll
        for (int j = 0; j < 4; ++j) {
          const int gr = row0 + m * 16 + l4 * 4 + j;
          const float v = acc[m][n][j];
          if constexpr (MODE == 3) {
            o0[(size_t)gr * F_N + gc] = f2bf(fmaxf(v + bv, 0.f));
          } else {
            fout[(size_t)gr * E_N + gc] = v + bv;
          }
        }
    }
  }
}

// ---------------- fused complex flash attention ----------------
// 512 threads = 8 waves, each owning 16 q-cols of a 128-q block; KV staged
// in 64-wide tiles (reg-prefetched), processed as two 32-t sub-steps.
// Scores in exp2 domain (log2e folded into Kc), imag in revolutions
// (1/2pi folded into Ks). Defer-max rescale (THR=8 log2 units).
__global__ __launch_bounds__(512, 4) void attn_kernel(
    const u16* __restrict__ Qg, const u16* __restrict__ Kcg,
    const u16* __restrict__ Ksg, const u16* __restrict__ Vcg,
    const u16* __restrict__ Vsg, float* __restrict__ outp) {
  __shared__ u16 KcS[64 * 64], KsS[64 * 64];
  __shared__ u16 VcS[64 * 64], VsS[64 * 64], VnS[64 * 64];
  __shared__ u16 PreS[128 * 32], PimS[128 * 32];

  const int tid = threadIdx.x;
  const int lane = tid & 63, wv = tid >> 6;
  const int l15 = lane & 15, l4 = lane >> 4;
  const int qt = blockIdx.x, hh = blockIdx.y, bb = blockIdx.z;
  const size_t hoff = ((size_t)(bb * H_N + hh)) * (size_t)(S_N * D_N);
  const u16* Kc = Kcg + hoff;
  const u16* Ks = Ksg + hoff;
  const u16* Vc = Vcg + hoff;
  const u16* Vs = Vsg + hoff;
  const int qrow = wv * 16 + l15;

  u16x8 qf[2];
#pragma unroll
  for (int ks = 0; ks < 2; ++ks)
    qf[ks] = *(const u16x8*)(Qg + hoff + (size_t)(qt * 128 + qrow) * D_N + ks * 32 + l4 * 8);

  f32x4 z4 = {0.f, 0.f, 0.f, 0.f};
  f32x4 Nre[4], Nim[4];
#pragma unroll
  for (int db = 0; db < 4; ++db) { Nre[db] = z4; Nim[db] = z4; }
  float mm = -1e30f, zre = 0.f, zim = 0.f;

  const int srow = tid >> 3, sc16 = tid & 7;
  const int skoff = (srow * 128 + sc16 * 16) ^ ((srow & 7) << 4);
  const u32x4 smask = {0x80008000u, 0x80008000u, 0x80008000u, 0x80008000u};

  // prefetch tile 0
  u32x4 rkc = *(const u32x4*)(Kc + (size_t)srow * 64 + sc16 * 8);
  u32x4 rks = *(const u32x4*)(Ks + (size_t)srow * 64 + sc16 * 8);
  u32x4 rvc = *(const u32x4*)(Vc + (size_t)srow * S_N + sc16 * 8);
  u32x4 rvs = *(const u32x4*)(Vs + (size_t)srow * S_N + sc16 * 8);

  for (int kt = 0; kt < 16; ++kt) {
    *(u32x4*)((char*)KcS + skoff) = rkc;
    *(u32x4*)((char*)KsS + skoff) = rks;
    *(u32x4*)((char*)VcS + skoff) = rvc;
    *(u32x4*)((char*)VsS + skoff) = rvs;
    *(u32x4*)((char*)VnS + skoff) = rvs ^ smask;
    if (kt < 15) {  // T14: issue next-tile loads under this tile's compute
      rkc = *(const u32x4*)(Kc + (size_t)((kt + 1) * 64 + srow) * 64 + sc16 * 8);
      rks = *(const u32x4*)(Ks + (size_t)((kt + 1) * 64 + srow) * 64 + sc16 * 8);
      rvc = *(const u32x4*)(Vc + (size_t)srow * S_N + (kt + 1) * 64 + sc16 * 8);
      rvs = *(const u32x4*)(Vs + (size_t)srow * S_N + (kt + 1) * 64 + sc16 * 8);
    }
    __syncthreads();

#pragma unroll
    for (int ts = 0; ts < 2; ++ts) {
      f32x4 sre[2], sim[2];
      sre[0] = z4; sre[1] = z4; sim[0] = z4; sim[1] = z4;
      __builtin_amdgcn_s_setprio(1);
#pragma unroll
      for (int tb = 0; tb < 2; ++tb) {
        const int trow = ts * 32 + tb * 16 + l15;
#pragma unroll
        for (int ks = 0; ks < 2; ++ks) {
          const int off = (trow * 128 + ks * 64 + (l4 << 4)) ^ ((trow & 7) << 4);
          u16x8 akc = *(const u16x8*)((const char*)KcS + off);
          u16x8 aks = *(const u16x8*)((const char*)KsS + off);
          sre[tb] = mfma16(akc, qf[ks], sre[tb]);
          sim[tb] = mfma16(aks, qf[ks], sim[tb]);
        }
      }
      __builtin_amdgcn_s_setprio(0);

      float tm = fmaxf(fmaxf(fmaxf(sre[0][0], sre[0][1]), fmaxf(sre[0][2], sre[0][3])),
                       fmaxf(fmaxf(sre[1][0], sre[1][1]), fmaxf(sre[1][2], sre[1][3])));
      tm = fmaxf(tm, __shfl_xor(tm, 16));
      tm = fmaxf(tm, __shfl_xor(tm, 32));
      if (__ballot(tm > mm + 8.f) != 0ull) {
        const float mn = fmaxf(mm, tm);
        const float sc = exp2_hw(mm - mn);
        mm = mn;
        zre *= sc; zim *= sc;
#pragma unroll
        for (int db = 0; db < 4; ++db) { Nre[db] *= sc; Nim[db] *= sc; }
      }

#pragma unroll
      for (int tb = 0; tb < 2; ++tb) {
        float pc[4], ps[4];
#pragma unroll
        for (int j = 0; j < 4; ++j) {
          const float e = exp2_hw(sre[tb][j] - mm);
          const float sn = sin_hw(sim[tb][j]);
          const float cs = cos_hw(sim[tb][j]);
          pc[j] = e * cs; ps[j] = e * sn;
        }
        zre += (pc[0] + pc[1]) + (pc[2] + pc[3]);
        zim += (ps[0] + ps[1]) + (ps[2] + ps[3]);
        u32x2 wre = {cvtpk(pc[0], pc[1]), cvtpk(pc[2], pc[3])};
        u32x2 wim = {cvtpk(ps[0], ps[1]), cvtpk(ps[2], ps[3])};
        const int offp = (qrow * 64 + tb * 32 + l4 * 8) ^ (((qrow >> 1) & 3) << 4);
        *(u32x2*)((char*)PreS + offp) = wre;
        *(u32x2*)((char*)PimS + offp) = wim;
      }

      // PV: P tiles are wave-private (rows wv*16..+16), no barrier needed.
      const int offp2 = (qrow * 64 + (l4 << 4)) ^ (((qrow >> 1) & 3) << 4);
      u16x8 bre = *(const u16x8*)((const char*)PreS + offp2);
      u16x8 bim = *(const u16x8*)((const char*)PimS + offp2);
      __builtin_amdgcn_s_setprio(1);
#pragma unroll
      for (int db = 0; db < 4; ++db) {
        const int vrow = db * 16 + l15;
        const int offv = (vrow * 128 + ts * 64 + (l4 << 4)) ^ ((vrow & 7) << 4);
        u16x8 avc = *(const u16x8*)((const char*)VcS + offv);
        u16x8 avs = *(const u16x8*)((const char*)VsS + offv);
        u16x8 avn = *(const u16x8*)((const char*)VnS + offv);
        Nre[db] = mfma16(avc, bre, Nre[db]);
        Nre[db] = mfma16(avn, bim, Nre[db]);
        Nim[db] = mfma16(avs, bre, Nim[db]);
        Nim[db] = mfma16(avc, bim, Nim[db]);
      }
      __builtin_amdgcn_s_setprio(0);
    }
    __syncthreads();
  }

  float zr = zre, zi = zim;
  zr += __shfl_xor(zr, 16); zr += __shfl_xor(zr, 32);
  zi += __shfl_xor(zi, 16); zi += __shfl_xor(zi, 32);
  const float inv = 1.f / (zr * zr + zi * zi);
  const int q = qt * 128 + qrow;
  float* orow = outp + ((size_t)(bb * S_N + q)) * E_N + hh * 64;
#pragma unroll
  for (int db = 0; db < 4; ++db) {
    float4 o;
    o.x = (Nre[db][0] * zr + Nim[db][0] * zi) * inv;
    o.y = (Nre[db][1] * zr + Nim[db][1] * zi) * inv;
    o.z = (Nre[db][2] * zr + Nim[db][2] * zi) * inv;
    o.w = (Nre[db][3] * zr + Nim[db][3] * zi) * inv;
    *(float4*)(orow + db * 16 + l4 * 4) = o;
  }
}

// ---------------- residual add + LayerNorm ----------------
__global__ __launch_bounds__(256) void add_ln_kernel(
    const float* __restrict__ a, const float* __restrict__ r,
    const float* __restrict__ g, const float* __restrict__ be,
    float* __restrict__ outf, u16* __restrict__ outb) {
  const int tid = threadIdx.x;
  const int row = blockIdx.x;
  const int lane = tid & 63, wv = tid >> 6;
  const float4 va = ((const float4*)(a + (size_t)row * 1024))[tid];
  const float4 vr = ((const float4*)(r + (size_t)row * 1024))[tid];
  float4 v;
  v.x = va.x + vr.x; v.y = va.y + vr.y; v.z = va.z + vr.z; v.w = va.w + vr.w;
  float s = v.x + v.y + v.z + v.w;
#pragma unroll
  for (int m = 1; m < 64; m <<= 1) s += __shfl_xor(s, m);
  __shared__ float red[8];
  if (lane == 0) red[wv] = s;
  __syncthreads();
  s = red[0] + red[1] + red[2] + red[3];
  const float mu = s * (1.f / 1024.f);
  float4 xc;
  xc.x = v.x - mu; xc.y = v.y - mu; xc.z = v.z - mu; xc.w = v.w - mu;
  float q = xc.x * xc.x + xc.y * xc.y + xc.z * xc.z + xc.w * xc.w;
#pragma unroll
  for (int m = 1; m < 64; m <<= 1) q += __shfl_xor(q, m);
  if (lane == 0) red[4 + wv] = q;
  __syncthreads();
  q = red[4] + red[5] + red[6] + red[7];
  const float rs = rsqrtf(q * (1.f / 1024.f) + 1e-5f);
  const float4 gg = ((const float4*)g)[tid];
  const float4 bb4 = ((const float4*)be)[tid];
  float4 o;
  o.x = xc.x * rs * gg.x + bb4.x;
  o.y = xc.y * rs * gg.y + bb4.y;
  o.z = xc.z * rs * gg.z + bb4.z;
  o.w = xc.w * rs * gg.w + bb4.w;
  if (outf) ((float4*)(outf + (size_t)row * 1024))[tid] = o;
  if (outb) {
    u16x4 ob;
    ob[0] = f2bf(o.x); ob[1] = f2bf(o.y); ob[2] = f2bf(o.z); ob[3] = f2bf(o.w);
    *(u16x4*)(outb + (size_t)row * 1024 + tid * 4) = ob;
  }
}

extern "C" void kernel_launch(void* const* d_in, const int* in_sizes, int n_in,
                              void* d_out, int out_size, void* d_ws, size_t ws_size,
                              hipStream_t stream) {
  (void)in_sizes; (void)n_in; (void)out_size; (void)ws_size;
  const float* x = (const float*)d_in[0];
  const float* wq = (const float*)d_in[1];
  const float* wk = (const float*)d_in[2];
  const float* wvp = (const float*)d_in[3];
  const float* phase = (const float*)d_in[4];
  const float* ln1g = (const float*)d_in[5];
  const float* ln1b = (const float*)d_in[6];
  const float* ln2g = (const float*)d_in[7];
  const float* ln2b = (const float*)d_in[8];
  const float* w1 = (const float*)d_in[9];
  const float* b1 = (const float*)d_in[10];
  const float* w2 = (const float*)d_in[11];
  const float* b2 = (const float*)d_in[12];
  float* outp = (float*)d_out;

  char* p = (char*)d_ws;
  auto alloc = [&](size_t n) -> char* {
    char* q = p;
    p += (n + 255) & ~(size_t)255;
    return q;
  };
  const size_t TOKE = (size_t)NTOK * E_N;  // 4M elements
  u16* xb = (u16*)alloc(TOKE * 2);
  u16* wqb = (u16*)alloc((size_t)E_N * E_N * 2);
  u16* wkb = (u16*)alloc((size_t)E_N * E_N * 2);
  u16* wvb = (u16*)alloc((size_t)E_N * E_N * 2);
  u16* w1b = (u16*)alloc((size_t)F_N * E_N * 2);
  u16* w2b = (u16*)alloc((size_t)E_N * F_N * 2);
  u16* Qp = (u16*)alloc(TOKE * 2);
  u16* Kcp = (u16*)alloc(TOKE * 2);
  u16* Ksp = (u16*)alloc(TOKE * 2);
  u16* Vcp = (u16*)alloc(TOKE * 2);
  u16* Vsp = (u16*)alloc(TOKE * 2);
  float* attn_o = (float*)alloc(TOKE * 4);
  float* x1f = (float*)alloc(TOKE * 4);
  // buffer reuse (lifetimes disjoint):
  u16* x1b = xb;        // xb dead after QKV projection
  u16* hb = Qp;         // Q/Kc/Ks/Vc (32MB) dead after attention
  float* ffn = attn_o;  // attn_o dead after LN1

  dim3 blk(256);
  cvt_all<<<dim3(4096, 6), blk, 0, stream>>>(
      x, xb, (int)(TOKE / 4),
      wq, wqb, E_N * E_N / 4,
      wk, wkb, E_N * E_N / 4,
      wvp, wvb, E_N * E_N / 4,
      w1, w1b, F_N * E_N / 4,
      w2, w2b, E_N * F_N / 4);

  gemm_bt<5, 128><<<dim3(24, 32), blk, 0, stream>>>(
      xb, wqb, wkb, wvb, E_N, nullptr, Qp, Kcp, Ksp, Vcp, Vsp, phase, nullptr);

  attn_kernel<<<dim3(8, 16, 4), dim3(512), 0, stream>>>(Qp, Kcp, Ksp, Vcp, Vsp, attn_o);

  add_ln_kernel<<<dim3(NTOK), blk, 0, stream>>>(x, attn_o, ln1g, ln1b, x1f, x1b);

  gemm_bt<3, 128><<<dim3(32, 32), blk, 0, stream>>>(
      x1b, w1b, nullptr, nullptr, E_N, nullptr, hb, nullptr, nullptr, nullptr,
      nullptr, nullptr, b1);
  gemm_bt<4, 64><<<dim3(16, 32), blk, 0, stream>>>(
      hb, w2b, nullptr, nullptr, F_N, ffn, nullptr, nullptr, nullptr, nullptr,
      nullptr, nullptr, b2);

  add_ln_kernel<<<dim3(NTOK), blk, 0, stream>>>(x1f, ffn, ln2g, ln2b, outp, nullptr);
}